// Round 2
// baseline (2741.469 us; speedup 1.0000x reference)
//
#include <hip/hip_runtime.h>
#include <hip/hip_cooperative_groups.h>
#include <math.h>

namespace cg = cooperative_groups;

#define BB 4
#define CC 132
#define TT 32
#define NN 64
#define HIDD 256
#define G4 1024
#define CIN 392
#define KK 16
#define HOFF 136   // CC + OFF: start of h columns in W

__device__ __forceinline__ float fsigm(float x) { return 1.0f / (1.0f + __expf(-x)); }
__device__ __forceinline__ float ftanh(float x) { float e = __expf(2.0f * x); return 1.0f - 2.0f / (e + 1.0f); }

// ---------------------------------------------------------------------------
// W[g][c] -> WT[c][g]. grid = 7*16 = 112 blocks, 64x64 tiles via LDS.
// ---------------------------------------------------------------------------
__global__ __launch_bounds__(256) void ktrans(const float* __restrict__ W,
                                              float* __restrict__ WT) {
    __shared__ float T[64][65];
    int c0 = (blockIdx.x >> 4) * 64, g0 = (blockIdx.x & 15) * 64;
    int tl = threadIdx.x & 63, th = threadIdx.x >> 6;
    for (int i = 0; i < 16; ++i) {
        int g = i * 4 + th;
        int c = c0 + tl;
        if (c < CIN) T[g][tl] = W[(size_t)(g0 + g) * CIN + c];
    }
    __syncthreads();
    for (int i = 0; i < 16; ++i) {
        int c = i * 4 + th;
        if (c0 + c < CIN) WT[(size_t)(c0 + c) * G4 + g0 + tl] = T[tl][c];
    }
}

// ---------------------------------------------------------------------------
// Top-k for all t. grid = B*T (128), block = 256 (4 waves x 16 n each).
// Lane = candidate m. key = (bits(d)<<32)|m; 64-lane bitonic ascending sort
// == stable top-k (smallest d first, ties -> lower index). d arithmetic is
// bit-identical to round 1 (which matched the np reference exactly).
// ---------------------------------------------------------------------------
__global__ __launch_bounds__(256) void ktopk(const float* __restrict__ in,
                                             int* __restrict__ idxw,
                                             float* __restrict__ outI) {
    int b = blockIdx.x & 3, t = blockIdx.x >> 2, tprev = t ? t - 1 : 0;
    int lane = threadIdx.x & 63, w = threadIdx.x >> 6;
    const float* base = in + (size_t)b * CC * TT * NN;
    float p0 = base[(0 * TT + tprev) * NN + lane];
    float p1 = base[(1 * TT + tprev) * NN + lane];
    float p2 = base[(2 * TT + tprev) * NN + lane];
    float q0 = base[(0 * TT + t) * NN + lane];
    float q1 = base[(1 * TT + t) * NN + lane];
    float q2 = base[(2 * TT + t) * NN + lane];
    for (int nn = 0; nn < 16; ++nn) {
        int n = w * 16 + nn;
        float a0 = __shfl(q0, n), a1 = __shfl(q1, n), a2 = __shfl(q2, n);
        float dx = a0 - p0, dy = a1 - p1, dz = a2 - p2;
        float s01 = __fadd_rn(__fmul_rn(dx, dx), __fmul_rn(dy, dy));
        float d = __fadd_rn(s01, __fmul_rn(dz, dz));
        unsigned long long key =
            ((unsigned long long)__float_as_uint(d) << 32) | (unsigned)lane;
        #pragma unroll
        for (int k = 2; k <= 64; k <<= 1) {
            #pragma unroll
            for (int j = k >> 1; j > 0; j >>= 1) {
                unsigned long long other = __shfl_xor(key, j);
                bool up = (lane & k) == 0;
                bool upper = (lane & j) != 0;
                bool keepMax = up ? upper : !upper;
                unsigned long long mn = key < other ? key : other;
                unsigned long long mx = key < other ? other : key;
                key = keepMax ? mx : mn;
            }
        }
        if (lane < KK) {
            int m = (int)(key & 0xffffffffu);
            idxw[((t * BB + b) * NN + n) * KK + lane] = m;
            outI[((b * TT + t) * NN + n) * KK + lane] = (float)m;
        }
    }
}

// ---------------------------------------------------------------------------
// XA[t][b][n][g] = sum_{c<132} W[g,c]*x[b,c,t,n] + bias[g]
//                - sum_{c<4} W[g,132+c]*x[b,c,t,n]
// Pure-register GEMM via WT. grid = 2048 (16 gt x 4 b x 32 t), block = 256.
// Thread tile 4n x 4g; both streams coalesced float4 from L1/L2.
// ---------------------------------------------------------------------------
__global__ __launch_bounds__(256) void kxa2(const float* __restrict__ in,
                                            const float* __restrict__ WT,
                                            const float* __restrict__ bias,
                                            float* __restrict__ XA) {
    int gt = blockIdx.x & 15, b = (blockIdx.x >> 4) & 3, t = blockIdx.x >> 6;
    int g0 = gt * 64;
    int tg = threadIdx.x & 15, tm = threadIdx.x >> 4;  // g=g0+tg*4, n=tm*4
    const float* xb = in + ((size_t)b * CC * TT + t) * NN;
    float4 a0 = {0, 0, 0, 0}, a1 = a0, a2 = a0, a3 = a0;
    #pragma unroll 4
    for (int c = 0; c < CC; ++c) {
        float4 wv = *(const float4*)&WT[(size_t)c * G4 + g0 + tg * 4];
        float4 xv = *(const float4*)&xb[(size_t)c * TT * NN + tm * 4];
        a0.x += xv.x * wv.x; a0.y += xv.x * wv.y; a0.z += xv.x * wv.z; a0.w += xv.x * wv.w;
        a1.x += xv.y * wv.x; a1.y += xv.y * wv.y; a1.z += xv.y * wv.z; a1.w += xv.y * wv.w;
        a2.x += xv.z * wv.x; a2.y += xv.z * wv.y; a2.z += xv.z * wv.z; a2.w += xv.z * wv.w;
        a3.x += xv.w * wv.x; a3.y += xv.w * wv.y; a3.z += xv.w * wv.z; a3.w += xv.w * wv.w;
    }
    #pragma unroll
    for (int c = 0; c < 4; ++c) {  // subtract pt * W[:,132+c]
        float4 wv = *(const float4*)&WT[(size_t)(CC + c) * G4 + g0 + tg * 4];
        float4 xv = *(const float4*)&xb[(size_t)c * TT * NN + tm * 4];
        a0.x -= xv.x * wv.x; a0.y -= xv.x * wv.y; a0.z -= xv.x * wv.z; a0.w -= xv.x * wv.w;
        a1.x -= xv.y * wv.x; a1.y -= xv.y * wv.y; a1.z -= xv.y * wv.z; a1.w -= xv.y * wv.w;
        a2.x -= xv.z * wv.x; a2.y -= xv.z * wv.y; a2.z -= xv.z * wv.z; a2.w -= xv.z * wv.w;
        a3.x -= xv.w * wv.x; a3.y -= xv.w * wv.y; a3.z -= xv.w * wv.z; a3.w -= xv.w * wv.w;
    }
    float4 bv = *(const float4*)&bias[g0 + tg * 4];
    a0.x += bv.x; a0.y += bv.y; a0.z += bv.z; a0.w += bv.w;
    a1.x += bv.x; a1.y += bv.y; a1.z += bv.z; a1.w += bv.w;
    a2.x += bv.x; a2.y += bv.y; a2.z += bv.z; a2.w += bv.w;
    a3.x += bv.x; a3.y += bv.y; a3.z += bv.z; a3.w += bv.w;
    size_t ob = (((size_t)t * BB + b) * NN + tm * 4) * G4 + g0 + tg * 4;
    *(float4*)&XA[ob] = a0;
    *(float4*)&XA[ob + G4] = a1;
    *(float4*)&XA[ob + 2 * G4] = a2;
    *(float4*)&XA[ob + 3 * G4] = a3;
}

// ---------------------------------------------------------------------------
// Cooperative t-loop. grid = 256 blocks x 256 threads, 2 grid.sync per step.
// Phase A (HP partial GEMM, split-K): bid -> (kc 4, gt 16, b 4).
//   HPp[kc][b][m][g] = sum_{c in kc-slice} WT[136+c][g]*hT[b][c][m]
//                    (+ pos part, kc==0 only). Pure registers, no LDS.
// Phase B (cell): bid -> (b 64n). gate = XA + sum_kc HPp; LSTM + max over K.
// ---------------------------------------------------------------------------
__global__ __launch_bounds__(256) void kloop(const float* __restrict__ in,
                                             const float* __restrict__ WT,
                                             const float* __restrict__ XA,
                                             const int* __restrict__ idxw,
                                             float* __restrict__ HPp,
                                             float* __restrict__ hT0,
                                             float* __restrict__ hT1,
                                             float* __restrict__ c0,
                                             float* __restrict__ c1,
                                             float* __restrict__ out) {
    cg::grid_group grid = cg::this_grid();
    int bid = blockIdx.x, tid = threadIdx.x;
    // phase A ids
    int ab = bid & 3, agt = (bid >> 2) & 15, akc = bid >> 6;
    int ag0 = agt * 64;
    int tg = tid & 15, tm = tid >> 4;  // g = ag0+tg*4 ; m = tm*4+j
    // phase B ids
    int bb = bid >> 6, bn = bid & 63;
    const size_t KSTRIDE = (size_t)BB * NN * G4;  // 262144

    for (int t = 0; t < TT; ++t) {
        // ---------------- phase A ----------------
        {
            int tprev = t ? t - 1 : 0;
            float4 acc[4];
            #pragma unroll
            for (int j = 0; j < 4; ++j) acc[j] = make_float4(0.f, 0.f, 0.f, 0.f);
            if (akc == 0) {
                #pragma unroll
                for (int c = 0; c < 4; ++c) {
                    float4 wv = *(const float4*)&WT[(size_t)(CC + c) * G4 + ag0 + tg * 4];
                    float4 pv = *(const float4*)&in[(((size_t)ab * CC + c) * TT + tprev) * NN + tm * 4];
                    float pj[4] = {pv.x, pv.y, pv.z, pv.w};
                    #pragma unroll
                    for (int j = 0; j < 4; ++j) {
                        acc[j].x += pj[j] * wv.x; acc[j].y += pj[j] * wv.y;
                        acc[j].z += pj[j] * wv.z; acc[j].w += pj[j] * wv.w;
                    }
                }
            }
            if (t > 0) {
                const float* hr = (t & 1) ? hT0 : hT1;  // written at t-1
                const float* hrow = hr + ((size_t)ab * HIDD + akc * 64) * NN;
                const float* wrow = WT + (size_t)(HOFF + akc * 64) * G4 + ag0 + tg * 4;
                #pragma unroll 4
                for (int cc = 0; cc < 64; ++cc) {
                    float4 wv = *(const float4*)&wrow[(size_t)cc * G4];
                    float4 hv = *(const float4*)&hrow[cc * NN + tm * 4];
                    float hj[4] = {hv.x, hv.y, hv.z, hv.w};
                    #pragma unroll
                    for (int j = 0; j < 4; ++j) {
                        acc[j].x += hj[j] * wv.x; acc[j].y += hj[j] * wv.y;
                        acc[j].z += hj[j] * wv.z; acc[j].w += hj[j] * wv.w;
                    }
                }
            }
            float* hp = HPp + (((size_t)akc * BB + ab) * NN + tm * 4) * G4 + ag0 + tg * 4;
            *(float4*)&hp[0] = acc[0];
            *(float4*)&hp[G4] = acc[1];
            *(float4*)&hp[2 * G4] = acc[2];
            *(float4*)&hp[3 * G4] = acc[3];
        }
        grid.sync();
        // ---------------- phase B ----------------
        {
            const float* xa = XA + (((size_t)t * BB + bb) * NN + bn) * G4 + tid;
            float xa0 = xa[0], xa1 = xa[256], xa2 = xa[512], xa3 = xa[768];
            const int* ib = idxw + ((t * BB + bb) * NN + bn) * KK;
            const float* cp = (t & 1) ? c0 : c1;
            float hmax = -INFINITY, cmax = -INFINITY;
            #pragma unroll 4
            for (int k = 0; k < KK; ++k) {
                int m = ib[k];
                const float* p = HPp + ((size_t)bb * NN + m) * G4 + tid;
                float gi = xa0 + p[0]   + p[KSTRIDE]       + p[2 * KSTRIDE]       + p[3 * KSTRIDE];
                float gf = xa1 + p[256] + p[KSTRIDE + 256] + p[2 * KSTRIDE + 256] + p[3 * KSTRIDE + 256];
                float go = xa2 + p[512] + p[KSTRIDE + 512] + p[2 * KSTRIDE + 512] + p[3 * KSTRIDE + 512];
                float gg = xa3 + p[768] + p[KSTRIDE + 768] + p[2 * KSTRIDE + 768] + p[3 * KSTRIDE + 768];
                float cg = (t > 0) ? cp[((size_t)bb * NN + m) * HIDD + tid] : 0.0f;
                float ck = fsigm(gf) * cg + fsigm(gi) * ftanh(gg);
                float hk = fsigm(go) * ftanh(ck);
                hmax = fmaxf(hmax, hk);
                cmax = fmaxf(cmax, ck);
            }
            float* cw = (t & 1) ? c1 : c0;
            float* hw = (t & 1) ? hT1 : hT0;
            cw[((size_t)bb * NN + bn) * HIDD + tid] = cmax;
            hw[((size_t)bb * HIDD + tid) * NN + bn] = hmax;           // transposed
            out[(((size_t)bb * HIDD + tid) * TT + t) * NN + bn] = hmax;
        }
        grid.sync();
    }
}

// ---------------------------------------------------------------------------
extern "C" void kernel_launch(void* const* d_in, const int* in_sizes, int n_in,
                              void* d_out, int out_size, void* d_ws, size_t ws_size,
                              hipStream_t stream) {
    const float* in   = (const float*)d_in[0];
    const float* W    = (const float*)d_in[2];
    const float* bias = (const float*)d_in[3];
    float* out  = (float*)d_out;
    float* outI = out + (size_t)BB * HIDD * TT * NN;  // 2,097,152

    float* ws  = (float*)d_ws;
    float* XA  = ws;                                   // 8,388,608 f
    float* WT  = XA + (size_t)TT * BB * NN * G4;       //   401,408 f
    float* HPp = WT + (size_t)CIN * G4;                // 1,048,576 f
    float* hT0 = HPp + (size_t)4 * BB * NN * G4;       //    65,536 f
    float* hT1 = hT0 + (size_t)BB * HIDD * NN;
    float* c0  = hT1 + (size_t)BB * HIDD * NN;
    float* c1  = c0 + (size_t)BB * NN * HIDD;
    int* idxw  = (int*)(c1 + (size_t)BB * NN * HIDD);  //   131,072 i

    ktrans<<<112, 256, 0, stream>>>(W, WT);
    ktopk<<<128, 256, 0, stream>>>(in, idxw, outI);
    kxa2<<<2048, 256, 0, stream>>>(in, WT, bias, XA);

    void* args[] = {(void*)&in, (void*)&WT, (void*)&XA, (void*)&idxw,
                    (void*)&HPp, (void*)&hT0, (void*)&hT1,
                    (void*)&c0, (void*)&c1, (void*)&out};
    hipLaunchCooperativeKernel((const void*)kloop, dim3(256), dim3(256),
                               args, 0, stream);
}

// Round 3
// 896.062 us; speedup vs baseline: 3.0595x; 3.0595x over previous
//
#include <hip/hip_runtime.h>
#include <math.h>

#define BB 4
#define CC 132
#define TT 32
#define NN 64
#define HIDD 256
#define G4 1024
#define CIN 392
#define KK 16
#define HOFF 136   // CC + OFF: start of h columns in W

__device__ __forceinline__ float fsigm(float x) { return 1.0f / (1.0f + __expf(-x)); }
__device__ __forceinline__ float ftanh(float x) { float e = __expf(2.0f * x); return 1.0f - 2.0f / (e + 1.0f); }

// ---------------------------------------------------------------------------
// W[g][c] -> WT[c][g]. grid = 7*16 = 112 blocks, 64x64 tiles via LDS.
// ---------------------------------------------------------------------------
__global__ __launch_bounds__(256) void ktrans(const float* __restrict__ W,
                                              float* __restrict__ WT) {
    __shared__ float T[64][65];
    int c0 = (blockIdx.x >> 4) * 64, g0 = (blockIdx.x & 15) * 64;
    int tl = threadIdx.x & 63, th = threadIdx.x >> 6;
    for (int i = 0; i < 16; ++i) {
        int g = i * 4 + th;
        int c = c0 + tl;
        if (c < CIN) T[g][tl] = W[(size_t)(g0 + g) * CIN + c];
    }
    __syncthreads();
    for (int i = 0; i < 16; ++i) {
        int c = i * 4 + th;
        if (c0 + c < CIN) WT[(size_t)(c0 + c) * G4 + g0 + tl] = T[tl][c];
    }
}

// ---------------------------------------------------------------------------
// Top-k for all t. grid = B*T (128), block = 256 (4 waves x 16 n each).
// Lane = candidate m. key = (bits(d)<<32)|m; 64-lane bitonic ascending sort
// == stable top-k (smallest d first, ties -> lower index). d arithmetic
// bit-identical to the np reference (no fma contraction, same add order).
// ---------------------------------------------------------------------------
__global__ __launch_bounds__(256) void ktopk(const float* __restrict__ in,
                                             int* __restrict__ idxw,
                                             float* __restrict__ outI) {
    int b = blockIdx.x & 3, t = blockIdx.x >> 2, tprev = t ? t - 1 : 0;
    int lane = threadIdx.x & 63, w = threadIdx.x >> 6;
    const float* base = in + (size_t)b * CC * TT * NN;
    float p0 = base[(0 * TT + tprev) * NN + lane];
    float p1 = base[(1 * TT + tprev) * NN + lane];
    float p2 = base[(2 * TT + tprev) * NN + lane];
    float q0 = base[(0 * TT + t) * NN + lane];
    float q1 = base[(1 * TT + t) * NN + lane];
    float q2 = base[(2 * TT + t) * NN + lane];
    for (int nn = 0; nn < 16; ++nn) {
        int n = w * 16 + nn;
        float a0 = __shfl(q0, n), a1 = __shfl(q1, n), a2 = __shfl(q2, n);
        float dx = a0 - p0, dy = a1 - p1, dz = a2 - p2;
        float s01 = __fadd_rn(__fmul_rn(dx, dx), __fmul_rn(dy, dy));
        float d = __fadd_rn(s01, __fmul_rn(dz, dz));
        unsigned long long key =
            ((unsigned long long)__float_as_uint(d) << 32) | (unsigned)lane;
        #pragma unroll
        for (int k = 2; k <= 64; k <<= 1) {
            #pragma unroll
            for (int j = k >> 1; j > 0; j >>= 1) {
                unsigned long long other = __shfl_xor(key, j);
                bool up = (lane & k) == 0;
                bool upper = (lane & j) != 0;
                bool keepMax = up ? upper : !upper;
                unsigned long long mn = key < other ? key : other;
                unsigned long long mx = key < other ? other : key;
                key = keepMax ? mx : mn;
            }
        }
        if (lane < KK) {
            int m = (int)(key & 0xffffffffu);
            idxw[((t * BB + b) * NN + n) * KK + lane] = m;
            outI[((b * TT + t) * NN + n) * KK + lane] = (float)m;
        }
    }
}

// ---------------------------------------------------------------------------
// XA[t][b][n][g] = sum_{c<132} W[g,c]*x[b,c,t,n] + bias[g]
//                - sum_{c<4} W[g,132+c]*x[b,c,t,n]
// Pure-register GEMM via WT. grid = 2048 (16 gt x 4 b x 32 t), block = 256.
// ---------------------------------------------------------------------------
__global__ __launch_bounds__(256) void kxa2(const float* __restrict__ in,
                                            const float* __restrict__ WT,
                                            const float* __restrict__ bias,
                                            float* __restrict__ XA) {
    int gt = blockIdx.x & 15, b = (blockIdx.x >> 4) & 3, t = blockIdx.x >> 6;
    int g0 = gt * 64;
    int tg = threadIdx.x & 15, tm = threadIdx.x >> 4;  // g=g0+tg*4, n=tm*4
    const float* xb = in + ((size_t)b * CC * TT + t) * NN;
    float4 a0 = {0, 0, 0, 0}, a1 = a0, a2 = a0, a3 = a0;
    #pragma unroll 4
    for (int c = 0; c < CC; ++c) {
        float4 wv = *(const float4*)&WT[(size_t)c * G4 + g0 + tg * 4];
        float4 xv = *(const float4*)&xb[(size_t)c * TT * NN + tm * 4];
        a0.x += xv.x * wv.x; a0.y += xv.x * wv.y; a0.z += xv.x * wv.z; a0.w += xv.x * wv.w;
        a1.x += xv.y * wv.x; a1.y += xv.y * wv.y; a1.z += xv.y * wv.z; a1.w += xv.y * wv.w;
        a2.x += xv.z * wv.x; a2.y += xv.z * wv.y; a2.z += xv.z * wv.z; a2.w += xv.z * wv.w;
        a3.x += xv.w * wv.x; a3.y += xv.w * wv.y; a3.z += xv.w * wv.z; a3.w += xv.w * wv.w;
    }
    #pragma unroll
    for (int c = 0; c < 4; ++c) {  // subtract pt * W[:,132+c]
        float4 wv = *(const float4*)&WT[(size_t)(CC + c) * G4 + g0 + tg * 4];
        float4 xv = *(const float4*)&xb[(size_t)c * TT * NN + tm * 4];
        a0.x -= xv.x * wv.x; a0.y -= xv.x * wv.y; a0.z -= xv.x * wv.z; a0.w -= xv.x * wv.w;
        a1.x -= xv.y * wv.x; a1.y -= xv.y * wv.y; a1.z -= xv.y * wv.z; a1.w -= xv.y * wv.w;
        a2.x -= xv.z * wv.x; a2.y -= xv.z * wv.y; a2.z -= xv.z * wv.z; a2.w -= xv.z * wv.w;
        a3.x -= xv.w * wv.x; a3.y -= xv.w * wv.y; a3.z -= xv.w * wv.z; a3.w -= xv.w * wv.w;
    }
    float4 bv = *(const float4*)&bias[g0 + tg * 4];
    a0.x += bv.x; a0.y += bv.y; a0.z += bv.z; a0.w += bv.w;
    a1.x += bv.x; a1.y += bv.y; a1.z += bv.z; a1.w += bv.w;
    a2.x += bv.x; a2.y += bv.y; a2.z += bv.z; a2.w += bv.w;
    a3.x += bv.x; a3.y += bv.y; a3.z += bv.z; a3.w += bv.w;
    size_t ob = (((size_t)t * BB + b) * NN + tm * 4) * G4 + g0 + tg * 4;
    *(float4*)&XA[ob] = a0;
    *(float4*)&XA[ob + G4] = a1;
    *(float4*)&XA[ob + 2 * G4] = a2;
    *(float4*)&XA[ob + 3 * G4] = a3;
}

// ---------------------------------------------------------------------------
// Per-step HP partial GEMM, register-only, split-K by 2.
// grid = 128: (gt 16) x (b 4) x (kc 2). block = 256, thread tile 4m x 4g.
// HPp[kc][b][m][g] = sum_{c in half} WT[136+c][g]*hT[b][c][m]
//                  (+ pos part when kc==0).  t==0: h-part skipped (h=0).
// ---------------------------------------------------------------------------
__global__ __launch_bounds__(256) void kh2(const float* __restrict__ in,
                                           const float* __restrict__ WT,
                                           const float* __restrict__ hT,
                                           float* __restrict__ HPp, int t) {
    int gt = blockIdx.x & 15, b = (blockIdx.x >> 4) & 3, kc = blockIdx.x >> 6;
    int g0 = gt * 64;
    int tg = threadIdx.x & 15, tm = threadIdx.x >> 4;  // g = g0+tg*4 ; m = tm*4+j
    int tprev = t ? t - 1 : 0;
    float4 acc[4];
    #pragma unroll
    for (int j = 0; j < 4; ++j) acc[j] = make_float4(0.f, 0.f, 0.f, 0.f);

    if (kc == 0) {
        #pragma unroll
        for (int c = 0; c < 4; ++c) {
            float4 wv = *(const float4*)&WT[(size_t)(CC + c) * G4 + g0 + tg * 4];
            float4 pv = *(const float4*)&in[(((size_t)b * CC + c) * TT + tprev) * NN + tm * 4];
            float pj[4] = {pv.x, pv.y, pv.z, pv.w};
            #pragma unroll
            for (int j = 0; j < 4; ++j) {
                acc[j].x += pj[j] * wv.x; acc[j].y += pj[j] * wv.y;
                acc[j].z += pj[j] * wv.z; acc[j].w += pj[j] * wv.w;
            }
        }
    }
    if (t > 0) {
        const float* hrow = hT + ((size_t)b * HIDD + kc * 128) * NN;
        const float* wrow = WT + (size_t)(HOFF + kc * 128) * G4 + g0 + tg * 4;
        #pragma unroll 4
        for (int cc = 0; cc < 128; ++cc) {
            float4 wv = *(const float4*)&wrow[(size_t)cc * G4];
            float4 hv = *(const float4*)&hrow[cc * NN + tm * 4];
            float hj[4] = {hv.x, hv.y, hv.z, hv.w};
            #pragma unroll
            for (int j = 0; j < 4; ++j) {
                acc[j].x += hj[j] * wv.x; acc[j].y += hj[j] * wv.y;
                acc[j].z += hj[j] * wv.z; acc[j].w += hj[j] * wv.w;
            }
        }
    }
    float* hp = HPp + (((size_t)kc * BB + b) * NN + tm * 4) * G4 + g0 + tg * 4;
    *(float4*)&hp[0] = acc[0];
    *(float4*)&hp[G4] = acc[1];
    *(float4*)&hp[2 * G4] = acc[2];
    *(float4*)&hp[3 * G4] = acc[3];
}

// ---------------------------------------------------------------------------
// LSTM cell + max over K, summing the 2 split-K partials.
// grid = B*N (256), block = 256 (thread = hid j).
// ---------------------------------------------------------------------------
__global__ __launch_bounds__(256) void kup2(const float* __restrict__ XA,
                                            const float* __restrict__ HPp,
                                            const int* __restrict__ idxw,
                                            const float* __restrict__ cprev,
                                            float* __restrict__ cnext,
                                            float* __restrict__ hT,
                                            float* __restrict__ out, int t) {
    int bb = blockIdx.x >> 6, bn = blockIdx.x & 63;
    int j = threadIdx.x;
    const size_t KSTR = (size_t)BB * NN * G4;  // 262144
    __shared__ int sidx[KK];
    if (j < KK) sidx[j] = idxw[((t * BB + bb) * NN + bn) * KK + j];
    __syncthreads();
    const float* xa = XA + (((size_t)t * BB + bb) * NN + bn) * G4 + j;
    float xa0 = xa[0], xa1 = xa[256], xa2 = xa[512], xa3 = xa[768];
    float hmax = -INFINITY, cmax = -INFINITY;
    #pragma unroll 4
    for (int k = 0; k < KK; ++k) {
        int m = sidx[k];
        const float* p = HPp + ((size_t)bb * NN + m) * G4 + j;
        float gi = xa0 + p[0]   + p[KSTR];
        float gf = xa1 + p[256] + p[KSTR + 256];
        float go = xa2 + p[512] + p[KSTR + 512];
        float gg = xa3 + p[768] + p[KSTR + 768];
        float cg = (t > 0) ? cprev[((size_t)bb * NN + m) * HIDD + j] : 0.0f;
        float ck = fsigm(gf) * cg + fsigm(gi) * ftanh(gg);
        float hk = fsigm(go) * ftanh(ck);
        hmax = fmaxf(hmax, hk);
        cmax = fmaxf(cmax, ck);
    }
    cnext[((size_t)bb * NN + bn) * HIDD + j] = cmax;
    hT[((size_t)bb * HIDD + j) * NN + bn] = hmax;            // transposed
    out[(((size_t)bb * HIDD + j) * TT + t) * NN + bn] = hmax;
}

// ---------------------------------------------------------------------------
extern "C" void kernel_launch(void* const* d_in, const int* in_sizes, int n_in,
                              void* d_out, int out_size, void* d_ws, size_t ws_size,
                              hipStream_t stream) {
    const float* in   = (const float*)d_in[0];
    const float* W    = (const float*)d_in[2];
    const float* bias = (const float*)d_in[3];
    float* out  = (float*)d_out;
    float* outI = out + (size_t)BB * HIDD * TT * NN;  // 2,097,152

    float* ws  = (float*)d_ws;
    float* XA  = ws;                                   // 8,388,608 f
    float* WT  = XA + (size_t)TT * BB * NN * G4;       //   401,408 f
    float* HPp = WT + (size_t)CIN * G4;                //   524,288 f (2 partials)
    float* hT  = HPp + (size_t)2 * BB * NN * G4;       //    65,536 f
    float* c0  = hT + (size_t)BB * HIDD * NN;          //    65,536 f
    float* c1  = c0 + (size_t)BB * NN * HIDD;          //    65,536 f
    int* idxw  = (int*)(c1 + (size_t)BB * NN * HIDD);  //   131,072 i

    ktrans<<<112, 256, 0, stream>>>(W, WT);
    ktopk<<<128, 256, 0, stream>>>(in, idxw, outI);
    kxa2<<<2048, 256, 0, stream>>>(in, WT, bias, XA);

    for (int t = 0; t < TT; ++t) {
        float* cp = (t & 1) ? c0 : c1;
        float* cn = (t & 1) ? c1 : c0;
        kh2<<<128, 256, 0, stream>>>(in, WT, hT, HPp, t);
        kup2<<<256, 256, 0, stream>>>(XA, HPp, idxw, cp, cn, hT, out, t);
    }
}

// Round 4
// 440.238 us; speedup vs baseline: 6.2272x; 2.0354x over previous
//
#include <hip/hip_runtime.h>
#include <math.h>

#define BB 4
#define CC 132
#define TT 32
#define NN 64
#define HIDD 256
#define G4 1024
#define CIN 392
#define KK 16
#define HOFF 136   // CC + OFF: start of h columns in W

typedef __attribute__((ext_vector_type(8))) short bf16x8;
typedef __attribute__((ext_vector_type(4))) float f32x4;

__device__ __forceinline__ float fsigm(float x) { return 1.0f / (1.0f + __expf(-x)); }
__device__ __forceinline__ float ftanh(float x) { float e = __expf(2.0f * x); return 1.0f - 2.0f / (e + 1.0f); }
__device__ __forceinline__ unsigned short f2bf(float x) {
    union { float f; unsigned u; } v; v.f = x;
    unsigned r = v.u + 0x7fffu + ((v.u >> 16) & 1u);   // RNE
    return (unsigned short)(r >> 16);
}

// ---------------------------------------------------------------------------
// W -> MFMA B-fragments.  WXf: K=160 (x 132 + pos 4 sign-folded + pad), per
// g-tile(16) x ks x lane: 8 bf16.  WHf: K=256 (h cols).  Wpos: f32 rows 132..136.
// grid = 64 (g-tiles), block = 256.
// ---------------------------------------------------------------------------
__global__ __launch_bounds__(256) void ktrans2(const float* __restrict__ W,
                                               unsigned short* __restrict__ WXf,
                                               unsigned short* __restrict__ WHf,
                                               float* __restrict__ Wpos) {
    int gt = blockIdx.x;
    int tid = threadIdx.x;
    __shared__ float Wl[16][CIN];
    for (int row = 0; row < 16; ++row)
        for (int c = tid; c < CIN; c += 256)
            Wl[row][c] = W[(size_t)(gt * 16 + row) * CIN + c];
    __syncthreads();
    for (int f = tid; f < 320; f += 256) {           // WXf: 5 ks x 64 lanes
        int ks = f >> 6, l = f & 63;
        bf16x8 v;
        #pragma unroll
        for (int j = 0; j < 8; ++j) {
            int c = ks * 32 + (l >> 4) * 8 + j;
            float w = (c < CC) ? Wl[l & 15][c] : ((c < HOFF) ? -Wl[l & 15][c] : 0.0f);
            v[j] = (short)f2bf(w);
        }
        *(bf16x8*)&WXf[((size_t)(gt * 5 + ks)) * 512 + l * 8] = v;
    }
    for (int f = tid; f < 512; f += 256) {           // WHf: 8 ks x 64 lanes
        int ks = f >> 6, l = f & 63;
        bf16x8 v;
        #pragma unroll
        for (int j = 0; j < 8; ++j) {
            int c = HOFF + ks * 32 + (l >> 4) * 8 + j;
            v[j] = (short)f2bf(Wl[l & 15][c]);
        }
        *(bf16x8*)&WHf[((size_t)(gt * 8 + ks)) * 512 + l * 8] = v;
    }
    if (tid < 64) {
        int c4 = tid >> 4, gl = tid & 15;
        Wpos[c4 * G4 + gt * 16 + gl] = Wl[gl][CC + c4];
    }
}

// ---------------------------------------------------------------------------
// Top-k for all t — bit-exact f32, unchanged from the passing round.
// ---------------------------------------------------------------------------
__global__ __launch_bounds__(256) void ktopk(const float* __restrict__ in,
                                             int* __restrict__ idxw,
                                             float* __restrict__ outI) {
    int b = blockIdx.x & 3, t = blockIdx.x >> 2, tprev = t ? t - 1 : 0;
    int lane = threadIdx.x & 63, w = threadIdx.x >> 6;
    const float* base = in + (size_t)b * CC * TT * NN;
    float p0 = base[(0 * TT + tprev) * NN + lane];
    float p1 = base[(1 * TT + tprev) * NN + lane];
    float p2 = base[(2 * TT + tprev) * NN + lane];
    float q0 = base[(0 * TT + t) * NN + lane];
    float q1 = base[(1 * TT + t) * NN + lane];
    float q2 = base[(2 * TT + t) * NN + lane];
    for (int nn = 0; nn < 16; ++nn) {
        int n = w * 16 + nn;
        float a0 = __shfl(q0, n), a1 = __shfl(q1, n), a2 = __shfl(q2, n);
        float dx = a0 - p0, dy = a1 - p1, dz = a2 - p2;
        float s01 = __fadd_rn(__fmul_rn(dx, dx), __fmul_rn(dy, dy));
        float d = __fadd_rn(s01, __fmul_rn(dz, dz));
        unsigned long long key =
            ((unsigned long long)__float_as_uint(d) << 32) | (unsigned)lane;
        #pragma unroll
        for (int k = 2; k <= 64; k <<= 1) {
            #pragma unroll
            for (int j = k >> 1; j > 0; j >>= 1) {
                unsigned long long other = __shfl_xor(key, j);
                bool up = (lane & k) == 0;
                bool upper = (lane & j) != 0;
                bool keepMax = up ? upper : !upper;
                unsigned long long mn = key < other ? key : other;
                unsigned long long mx = key < other ? other : key;
                key = keepMax ? mx : mn;
            }
        }
        if (lane < KK) {
            int m = (int)(key & 0xffffffffu);
            idxw[((t * BB + b) * NN + n) * KK + lane] = m;
            outI[((b * TT + t) * NN + n) * KK + lane] = (float)m;
        }
    }
}

// ---------------------------------------------------------------------------
// x -> A-fragments (bf16, K padded to 160). grid = 128 (t,b), block = 256.
// ---------------------------------------------------------------------------
__global__ __launch_bounds__(256) void kconvA(const float* __restrict__ in,
                                              unsigned short* __restrict__ xf) {
    int t = blockIdx.x >> 2, b = blockIdx.x & 3;
    int tid = threadIdx.x;
    __shared__ unsigned short X[64][160];
    int n = tid & 63, cg = tid >> 6;
    for (int c = cg; c < 160; c += 4) {
        float v = 0.0f;
        if (c < CC)        v = in[(((size_t)b * CC + c) * TT + t) * NN + n];
        else if (c < HOFF) v = in[(((size_t)b * CC + (c - CC)) * TT + t) * NN + n];
        X[n][c] = f2bf(v);
    }
    __syncthreads();
    for (int i = 0; i < 5; ++i) {          // 4 mtn x 5 ks x 64 l = 1280 frags
        int f = i * 256 + tid;
        int mtn = f / 320, r = f % 320;
        int ks = r >> 6, l = r & 63;
        uint4 v = *(const uint4*)&X[mtn * 16 + (l & 15)][ks * 32 + (l >> 4) * 8];
        *(uint4*)&xf[(((size_t)(blockIdx.x * 4 + mtn)) * 5 + ks) * 512 + l * 8] = v;
    }
}

// ---------------------------------------------------------------------------
// XA = x*Wx + b (MFMA). grid = 512 (4 gq x 128 tb), block = 256 (4 waves).
// Wave: 4 m-tiles x 4 g-tiles x 5 ks = 80 MFMA.
// ---------------------------------------------------------------------------
__global__ __launch_bounds__(256) void kxa3(const unsigned short* __restrict__ xf,
                                            const unsigned short* __restrict__ WXf,
                                            const float* __restrict__ bias,
                                            float* __restrict__ XA) {
    int gq = blockIdx.x & 3, tb = blockIdx.x >> 2;
    int w = threadIdx.x >> 6, l = threadIdx.x & 63;
    int gbase = gq * 16 + w * 4;
    f32x4 acc[4][4];
    #pragma unroll
    for (int a = 0; a < 4; ++a)
        #pragma unroll
        for (int g = 0; g < 4; ++g) acc[a][g] = (f32x4){0.f, 0.f, 0.f, 0.f};
    #pragma unroll
    for (int ks = 0; ks < 5; ++ks) {
        bf16x8 af[4], bfr[4];
        #pragma unroll
        for (int m = 0; m < 4; ++m)
            af[m] = *(const bf16x8*)&xf[(((size_t)(tb * 4 + m)) * 5 + ks) * 512 + l * 8];
        #pragma unroll
        for (int g = 0; g < 4; ++g)
            bfr[g] = *(const bf16x8*)&WXf[((size_t)((gbase + g) * 5 + ks)) * 512 + l * 8];
        #pragma unroll
        for (int m = 0; m < 4; ++m)
            #pragma unroll
            for (int g = 0; g < 4; ++g)
                acc[m][g] = __builtin_amdgcn_mfma_f32_16x16x32_bf16(af[m], bfr[g], acc[m][g], 0, 0, 0);
    }
    int rb = tb * 64;
    #pragma unroll
    for (int g = 0; g < 4; ++g) {
        int gcol = (gbase + g) * 16 + (l & 15);
        float bv = bias[gcol];
        #pragma unroll
        for (int m = 0; m < 4; ++m)
            #pragma unroll
            for (int r = 0; r < 4; ++r) {
                int row = rb + m * 16 + (l >> 4) * 4 + r;
                XA[(size_t)row * G4 + gcol] = acc[m][g][r] + bv;
            }
    }
}

// ---------------------------------------------------------------------------
// Per-step HP GEMM (MFMA, full K=256) + f32 pos epilogue.
// grid = 256 (16 gquad x 16 mt), block = 256 (4 waves, wave = 1 g-tile).
// ---------------------------------------------------------------------------
__global__ __launch_bounds__(256) void kh3(const float* __restrict__ in,
                                           const unsigned short* __restrict__ WHf,
                                           const unsigned short* __restrict__ hb,
                                           const float* __restrict__ Wpos,
                                           float* __restrict__ HP, int t) {
    int gquad = blockIdx.x & 15, mt = blockIdx.x >> 4;
    int w = threadIdx.x >> 6, l = threadIdx.x & 63;
    int gt = gquad * 4 + w;
    f32x4 acc = {0.f, 0.f, 0.f, 0.f};
    if (t > 0) {
        bf16x8 af[8], bfr[8];
        #pragma unroll
        for (int ks = 0; ks < 8; ++ks) {
            af[ks]  = *(const bf16x8*)&hb[((size_t)(mt * 8 + ks)) * 512 + l * 8];
            bfr[ks] = *(const bf16x8*)&WHf[((size_t)(gt * 8 + ks)) * 512 + l * 8];
        }
        #pragma unroll
        for (int ks = 0; ks < 8; ++ks)
            acc = __builtin_amdgcn_mfma_f32_16x16x32_bf16(af[ks], bfr[ks], acc, 0, 0, 0);
    }
    int tprev = t ? t - 1 : 0;
    int b = mt >> 2;
    int gcol = gt * 16 + (l & 15);
    #pragma unroll
    for (int c = 0; c < 4; ++c) {
        float wpc = Wpos[c * G4 + gcol];
        #pragma unroll
        for (int r = 0; r < 4; ++r) {
            int m = (mt & 3) * 16 + (l >> 4) * 4 + r;
            float p = in[(((size_t)b * CC + c) * TT + tprev) * NN + m];
            acc[r] += wpc * p;
        }
    }
    #pragma unroll
    for (int r = 0; r < 4; ++r)
        HP[(size_t)(mt * 16 + (l >> 4) * 4 + r) * G4 + gcol] = acc[r];
}

// ---------------------------------------------------------------------------
// LSTM cell + max over K, k split across 4 groups. grid = 256 (b,n),
// block = 1024 (kg 4 x j 256). Writes h in bf16 fragment order for kh3.
// ---------------------------------------------------------------------------
__global__ __launch_bounds__(1024) void kup3(const float* __restrict__ XA,
                                             const float* __restrict__ HP,
                                             const int* __restrict__ idxw,
                                             const float* __restrict__ cprev,
                                             float* __restrict__ cnext,
                                             unsigned short* __restrict__ hb,
                                             float* __restrict__ out, int t) {
    int b = blockIdx.x >> 6, n = blockIdx.x & 63;
    int kg = threadIdx.x >> 8, j = threadIdx.x & 255;
    __shared__ int sidx[KK];
    __shared__ float hps[3][HIDD], cps[3][HIDD];
    if (threadIdx.x < KK)
        sidx[threadIdx.x] = idxw[((size_t)(t * BB + b) * NN + n) * KK + threadIdx.x];
    __syncthreads();
    const float* xa = XA + ((size_t)(t * BB + b) * NN + n) * G4 + j;
    float xa0 = xa[0], xa1 = xa[256], xa2 = xa[512], xa3 = xa[768];
    float hmax = -INFINITY, cmax = -INFINITY;
    #pragma unroll
    for (int kk = 0; kk < 4; ++kk) {
        int m = sidx[kg * 4 + kk];
        const float* p = HP + (size_t)(b * NN + m) * G4 + j;
        float gi = xa0 + p[0];
        float gf = xa1 + p[256];
        float go = xa2 + p[512];
        float gg = xa3 + p[768];
        float cg = (t > 0) ? cprev[(size_t)(b * NN + m) * HIDD + j] : 0.0f;
        float ck = fsigm(gf) * cg + fsigm(gi) * ftanh(gg);
        float hk = fsigm(go) * ftanh(ck);
        hmax = fmaxf(hmax, hk);
        cmax = fmaxf(cmax, ck);
    }
    if (kg > 0) { hps[kg - 1][j] = hmax; cps[kg - 1][j] = cmax; }
    __syncthreads();
    if (kg == 0) {
        hmax = fmaxf(fmaxf(hmax, hps[0][j]), fmaxf(hps[1][j], hps[2][j]));
        cmax = fmaxf(fmaxf(cmax, cps[0][j]), fmaxf(cps[1][j], cps[2][j]));
        cnext[(size_t)(b * NN + n) * HIDD + j] = cmax;
        int row = b * NN + n;
        int mt = row >> 4, q = (j >> 3) & 3, ks = j >> 5;
        hb[((size_t)(mt * 8 + ks) * 64 + q * 16 + (row & 15)) * 8 + (j & 7)] = f2bf(hmax);
        out[((size_t)(b * HIDD + j) * TT + t) * NN + n] = hmax;
    }
}

// ---------------------------------------------------------------------------
extern "C" void kernel_launch(void* const* d_in, const int* in_sizes, int n_in,
                              void* d_out, int out_size, void* d_ws, size_t ws_size,
                              hipStream_t stream) {
    const float* in   = (const float*)d_in[0];
    const float* W    = (const float*)d_in[2];
    const float* bias = (const float*)d_in[3];
    float* out  = (float*)d_out;
    float* outI = out + (size_t)BB * HIDD * TT * NN;

    float* ws   = (float*)d_ws;
    float* XA   = ws;                                  // 8,388,608 f
    float* HP   = XA + (size_t)TT * BB * NN * G4;      //   262,144 f
    float* Wpos = HP + (size_t)BB * NN * G4;           //     4,096 f
    float* c0   = Wpos + 4 * G4;                       //    65,536 f
    float* c1   = c0 + (size_t)BB * NN * HIDD;         //    65,536 f
    unsigned short* WXf = (unsigned short*)(c1 + (size_t)BB * NN * HIDD); // 163,840 us
    unsigned short* WHf = WXf + (size_t)64 * 5 * 512;  // 262,144 us
    unsigned short* xf  = WHf + (size_t)64 * 8 * 512;  // 1,310,720 us
    unsigned short* hb  = xf + (size_t)128 * 4 * 5 * 512; // 65,536 us
    int* idxw = (int*)(hb + (size_t)BB * NN * HIDD);   // 131,072 i

    ktrans2<<<64, 256, 0, stream>>>(W, WXf, WHf, Wpos);
    ktopk<<<128, 256, 0, stream>>>(in, idxw, outI);
    kconvA<<<128, 256, 0, stream>>>(in, xf);
    kxa3<<<512, 256, 0, stream>>>(xf, WXf, bias, XA);

    for (int t = 0; t < TT; ++t) {
        float* cp = (t & 1) ? c0 : c1;
        float* cn = (t & 1) ? c1 : c0;
        kh3<<<256, 256, 0, stream>>>(in, WHf, hb, Wpos, HP, t);
        kup3<<<256, 1024, 0, stream>>>(XA, HP, idxw, cp, cn, hb, out, t);
    }
}

// Round 5
// 415.929 us; speedup vs baseline: 6.5912x; 1.0584x over previous
//
#include <hip/hip_runtime.h>
#include <math.h>

#define BB 4
#define CC 132
#define TT 32
#define NN 64
#define HIDD 256
#define G4 1024
#define CIN 392
#define KK 16
#define HOFF 136   // CC + OFF: start of h columns in W

typedef __attribute__((ext_vector_type(8))) short bf16x8;
typedef __attribute__((ext_vector_type(4))) float f32x4;

__device__ __forceinline__ float fsigm(float x) { return 1.0f / (1.0f + __expf(-x)); }
__device__ __forceinline__ float ftanh(float x) { float e = __expf(2.0f * x); return 1.0f - 2.0f / (e + 1.0f); }
__device__ __forceinline__ unsigned short f2bf(float x) {
    union { float f; unsigned u; } v; v.f = x;
    unsigned r = v.u + 0x7fffu + ((v.u >> 16) & 1u);   // RNE
    return (unsigned short)(r >> 16);
}
__device__ __forceinline__ float bf2f_lo(unsigned u) { return __uint_as_float(u << 16); }
__device__ __forceinline__ float bf2f_hi(unsigned u) { return __uint_as_float(u & 0xffff0000u); }

// ---------------------------------------------------------------------------
// W -> MFMA B-fragments with gate-interleaved column permutation:
//   g' = 4*j + gate  (orig row = gate*256 + j).
// WXf: K=160 (x 132 + pos 4 sign-folded + pad). WHf: K=256 (h cols).
// Wpos[c][g'], biasP[g'] also permuted. grid = 64 (g'-tiles of 16), block 256.
// ---------------------------------------------------------------------------
__global__ __launch_bounds__(256) void ktrans2(const float* __restrict__ W,
                                               const float* __restrict__ bias,
                                               unsigned short* __restrict__ WXf,
                                               unsigned short* __restrict__ WHf,
                                               float* __restrict__ Wpos,
                                               float* __restrict__ biasP) {
    int gt = blockIdx.x;
    int tid = threadIdx.x;
    __shared__ float Wl[16][CIN];
    for (int row = 0; row < 16; ++row) {
        int orig = (row & 3) * 256 + gt * 4 + (row >> 2);   // gate*256 + j
        for (int c = tid; c < CIN; c += 256)
            Wl[row][c] = W[(size_t)orig * CIN + c];
    }
    __syncthreads();
    for (int f = tid; f < 320; f += 256) {           // WXf: 5 ks x 64 lanes
        int ks = f >> 6, l = f & 63;
        bf16x8 v;
        #pragma unroll
        for (int j = 0; j < 8; ++j) {
            int c = ks * 32 + (l >> 4) * 8 + j;
            float w = (c < CC) ? Wl[l & 15][c] : ((c < HOFF) ? -Wl[l & 15][c] : 0.0f);
            v[j] = (short)f2bf(w);
        }
        *(bf16x8*)&WXf[((size_t)(gt * 5 + ks)) * 512 + l * 8] = v;
    }
    for (int f = tid; f < 512; f += 256) {           // WHf: 8 ks x 64 lanes
        int ks = f >> 6, l = f & 63;
        bf16x8 v;
        #pragma unroll
        for (int j = 0; j < 8; ++j) {
            int c = HOFF + ks * 32 + (l >> 4) * 8 + j;
            v[j] = (short)f2bf(Wl[l & 15][c]);
        }
        *(bf16x8*)&WHf[((size_t)(gt * 8 + ks)) * 512 + l * 8] = v;
    }
    if (tid < 64) {
        int c4 = tid >> 4, gl = tid & 15;
        Wpos[c4 * G4 + gt * 16 + gl] = Wl[gl][CC + c4];
    }
    if (tid < 16)
        biasP[gt * 16 + tid] = bias[(tid & 3) * 256 + gt * 4 + (tid >> 2)];
}

// ---------------------------------------------------------------------------
// Top-k for all t — bit-exact f32, unchanged (strictly-graded output).
// ---------------------------------------------------------------------------
__global__ __launch_bounds__(256) void ktopk(const float* __restrict__ in,
                                             int* __restrict__ idxw,
                                             float* __restrict__ outI) {
    int b = blockIdx.x & 3, t = blockIdx.x >> 2, tprev = t ? t - 1 : 0;
    int lane = threadIdx.x & 63, w = threadIdx.x >> 6;
    const float* base = in + (size_t)b * CC * TT * NN;
    float p0 = base[(0 * TT + tprev) * NN + lane];
    float p1 = base[(1 * TT + tprev) * NN + lane];
    float p2 = base[(2 * TT + tprev) * NN + lane];
    float q0 = base[(0 * TT + t) * NN + lane];
    float q1 = base[(1 * TT + t) * NN + lane];
    float q2 = base[(2 * TT + t) * NN + lane];
    for (int nn = 0; nn < 16; ++nn) {
        int n = w * 16 + nn;
        float a0 = __shfl(q0, n), a1 = __shfl(q1, n), a2 = __shfl(q2, n);
        float dx = a0 - p0, dy = a1 - p1, dz = a2 - p2;
        float s01 = __fadd_rn(__fmul_rn(dx, dx), __fmul_rn(dy, dy));
        float d = __fadd_rn(s01, __fmul_rn(dz, dz));
        unsigned long long key =
            ((unsigned long long)__float_as_uint(d) << 32) | (unsigned)lane;
        #pragma unroll
        for (int k = 2; k <= 64; k <<= 1) {
            #pragma unroll
            for (int j = k >> 1; j > 0; j >>= 1) {
                unsigned long long other = __shfl_xor(key, j);
                bool up = (lane & k) == 0;
                bool upper = (lane & j) != 0;
                bool keepMax = up ? upper : !upper;
                unsigned long long mn = key < other ? key : other;
                unsigned long long mx = key < other ? other : key;
                key = keepMax ? mx : mn;
            }
        }
        if (lane < KK) {
            int m = (int)(key & 0xffffffffu);
            idxw[((t * BB + b) * NN + n) * KK + lane] = m;
            outI[((b * TT + t) * NN + n) * KK + lane] = (float)m;
        }
    }
}

// ---------------------------------------------------------------------------
// x -> A-fragments (bf16, K padded to 160). grid = 128 (t,b), block = 256.
// ---------------------------------------------------------------------------
__global__ __launch_bounds__(256) void kconvA(const float* __restrict__ in,
                                              unsigned short* __restrict__ xf) {
    int t = blockIdx.x >> 2, b = blockIdx.x & 3;
    int tid = threadIdx.x;
    __shared__ unsigned short X[64][160];
    int n = tid & 63, cg = tid >> 6;
    for (int c = cg; c < 160; c += 4) {
        float v = 0.0f;
        if (c < CC)        v = in[(((size_t)b * CC + c) * TT + t) * NN + n];
        else if (c < HOFF) v = in[(((size_t)b * CC + (c - CC)) * TT + t) * NN + n];
        X[n][c] = f2bf(v);
    }
    __syncthreads();
    for (int i = 0; i < 5; ++i) {          // 4 mtn x 5 ks x 64 l = 1280 frags
        int f = i * 256 + tid;
        int mtn = f / 320, r = f % 320;
        int ks = r >> 6, l = r & 63;
        uint4 v = *(const uint4*)&X[mtn * 16 + (l & 15)][ks * 32 + (l >> 4) * 8];
        *(uint4*)&xf[(((size_t)(blockIdx.x * 4 + mtn)) * 5 + ks) * 512 + l * 8] = v;
    }
}

// ---------------------------------------------------------------------------
// XA = x*Wx + biasP (MFMA, permuted cols). grid = 512, block = 256 (4 waves).
// ---------------------------------------------------------------------------
__global__ __launch_bounds__(256) void kxa3(const unsigned short* __restrict__ xf,
                                            const unsigned short* __restrict__ WXf,
                                            const float* __restrict__ biasP,
                                            float* __restrict__ XA) {
    int gq = blockIdx.x & 3, tb = blockIdx.x >> 2;
    int w = threadIdx.x >> 6, l = threadIdx.x & 63;
    int gbase = gq * 16 + w * 4;
    f32x4 acc[4][4];
    #pragma unroll
    for (int a = 0; a < 4; ++a)
        #pragma unroll
        for (int g = 0; g < 4; ++g) acc[a][g] = (f32x4){0.f, 0.f, 0.f, 0.f};
    #pragma unroll
    for (int ks = 0; ks < 5; ++ks) {
        bf16x8 af[4], bfr[4];
        #pragma unroll
        for (int m = 0; m < 4; ++m)
            af[m] = *(const bf16x8*)&xf[(((size_t)(tb * 4 + m)) * 5 + ks) * 512 + l * 8];
        #pragma unroll
        for (int g = 0; g < 4; ++g)
            bfr[g] = *(const bf16x8*)&WXf[((size_t)((gbase + g) * 5 + ks)) * 512 + l * 8];
        #pragma unroll
        for (int m = 0; m < 4; ++m)
            #pragma unroll
            for (int g = 0; g < 4; ++g)
                acc[m][g] = __builtin_amdgcn_mfma_f32_16x16x32_bf16(af[m], bfr[g], acc[m][g], 0, 0, 0);
    }
    int rb = tb * 64;
    #pragma unroll
    for (int g = 0; g < 4; ++g) {
        int gcol = (gbase + g) * 16 + (l & 15);
        float bv = biasP[gcol];
        #pragma unroll
        for (int m = 0; m < 4; ++m)
            #pragma unroll
            for (int r = 0; r < 4; ++r) {
                int row = rb + m * 16 + (l >> 4) * 4 + r;
                XA[(size_t)row * G4 + gcol] = acc[m][g][r] + bv;
            }
    }
}

// ---------------------------------------------------------------------------
// Per-step HP GEMM (MFMA, K=256) + f32 pos epilogue -> bf16 packed HP.
// grid = 256 (16 gquad x 16 mt), block = 256 (4 waves, wave = 1 g'-tile).
// ---------------------------------------------------------------------------
__global__ __launch_bounds__(256) void kh3(const float* __restrict__ in,
                                           const unsigned short* __restrict__ WHf,
                                           const unsigned short* __restrict__ hb,
                                           const float* __restrict__ Wpos,
                                           unsigned short* __restrict__ HP16, int t) {
    int gquad = blockIdx.x & 15, mt = blockIdx.x >> 4;
    int w = threadIdx.x >> 6, l = threadIdx.x & 63;
    int gt = gquad * 4 + w;
    f32x4 acc = {0.f, 0.f, 0.f, 0.f};
    if (t > 0) {
        bf16x8 af[8], bfr[8];
        #pragma unroll
        for (int ks = 0; ks < 8; ++ks) {
            af[ks]  = *(const bf16x8*)&hb[((size_t)(mt * 8 + ks)) * 512 + l * 8];
            bfr[ks] = *(const bf16x8*)&WHf[((size_t)(gt * 8 + ks)) * 512 + l * 8];
        }
        #pragma unroll
        for (int ks = 0; ks < 8; ++ks)
            acc = __builtin_amdgcn_mfma_f32_16x16x32_bf16(af[ks], bfr[ks], acc, 0, 0, 0);
    }
    int tprev = t ? t - 1 : 0;
    int b = mt >> 2;
    int gcol = gt * 16 + (l & 15);
    #pragma unroll
    for (int c = 0; c < 4; ++c) {
        float wpc = Wpos[c * G4 + gcol];
        #pragma unroll
        for (int r = 0; r < 4; ++r) {
            int m = (mt & 3) * 16 + (l >> 4) * 4 + r;
            float p = in[(((size_t)b * CC + c) * TT + tprev) * NN + m];
            acc[r] += wpc * p;
        }
    }
    #pragma unroll
    for (int r = 0; r < 4; ++r)
        HP16[(size_t)(mt * 16 + (l >> 4) * 4 + r) * G4 + gcol] = f2bf(acc[r]);
}

// ---------------------------------------------------------------------------
// LSTM cell + max over K. grid = 256 (b,n), block = 1024 (kg 4 x j 256).
// Packed loads: XA float4, HP16 uint2 (4 bf16 gates). Writes h to staging
// (coalesced) + bf16 fragment buffer for next kh3.
// ---------------------------------------------------------------------------
__global__ __launch_bounds__(1024) void kup3(const float* __restrict__ XA,
                                             const unsigned short* __restrict__ HP16,
                                             const int* __restrict__ idxw,
                                             const float* __restrict__ cprev,
                                             float* __restrict__ cnext,
                                             unsigned short* __restrict__ hb,
                                             float* __restrict__ hstage, int t) {
    int b = blockIdx.x >> 6, n = blockIdx.x & 63;
    int kg = threadIdx.x >> 8, j = threadIdx.x & 255;
    __shared__ int sidx[KK];
    __shared__ float hps[3][HIDD], cps[3][HIDD];
    if (threadIdx.x < KK)
        sidx[threadIdx.x] = idxw[((size_t)(t * BB + b) * NN + n) * KK + threadIdx.x];
    __syncthreads();
    const float4 xav = *(const float4*)&XA[((size_t)(t * BB + b) * NN + n) * G4 + j * 4];
    float hmax = -INFINITY, cmax = -INFINITY;
    #pragma unroll
    for (int kk = 0; kk < 4; ++kk) {
        int m = sidx[kg * 4 + kk];
        uint2 hp = *(const uint2*)&HP16[((size_t)(b * NN + m) << 10) + (j << 2)];
        float gi = xav.x + bf2f_lo(hp.x);
        float gf = xav.y + bf2f_hi(hp.x);
        float go = xav.z + bf2f_lo(hp.y);
        float gg = xav.w + bf2f_hi(hp.y);
        float cg = (t > 0) ? cprev[(size_t)(b * NN + m) * HIDD + j] : 0.0f;
        float ck = fsigm(gf) * cg + fsigm(gi) * ftanh(gg);
        float hk = fsigm(go) * ftanh(ck);
        hmax = fmaxf(hmax, hk);
        cmax = fmaxf(cmax, ck);
    }
    if (kg > 0) { hps[kg - 1][j] = hmax; cps[kg - 1][j] = cmax; }
    __syncthreads();
    if (kg == 0) {
        hmax = fmaxf(fmaxf(hmax, hps[0][j]), fmaxf(hps[1][j], hps[2][j]));
        cmax = fmaxf(fmaxf(cmax, cps[0][j]), fmaxf(cps[1][j], cps[2][j]));
        cnext[(size_t)(b * NN + n) * HIDD + j] = cmax;
        int row = b * NN + n;
        int mt = row >> 4, q = (j >> 3) & 3, ks = j >> 5;
        hb[((size_t)(mt * 8 + ks) * 64 + q * 16 + (row & 15)) * 8 + (j & 7)] = f2bf(hmax);
        hstage[((size_t)(t * BB + b) * NN + n) * HIDD + j] = hmax;   // coalesced
    }
}

// ---------------------------------------------------------------------------
// hstage [t][b][n][j] -> out [b][j][t][n] via LDS transpose. grid = 128 (t,b).
// ---------------------------------------------------------------------------
__global__ __launch_bounds__(256) void kout(const float* __restrict__ hs,
                                            float* __restrict__ out) {
    int t = blockIdx.x >> 2, b = blockIdx.x & 3;
    __shared__ float T[64][65];
    int tl = threadIdx.x & 63, th = threadIdx.x >> 6;
    for (int jc = 0; jc < 4; ++jc) {
        __syncthreads();
        for (int i = 0; i < 16; ++i) {
            int n = i * 4 + th;
            T[n][tl] = hs[((size_t)(t * BB + b) * NN + n) * HIDD + jc * 64 + tl];
        }
        __syncthreads();
        for (int i = 0; i < 16; ++i) {
            int j = jc * 64 + i * 4 + th;
            out[((size_t)(b * HIDD + j) * TT + t) * NN + tl] = T[tl][i * 4 + th];
        }
    }
}

// ---------------------------------------------------------------------------
extern "C" void kernel_launch(void* const* d_in, const int* in_sizes, int n_in,
                              void* d_out, int out_size, void* d_ws, size_t ws_size,
                              hipStream_t stream) {
    const float* in   = (const float*)d_in[0];
    const float* W    = (const float*)d_in[2];
    const float* bias = (const float*)d_in[3];
    float* out  = (float*)d_out;
    float* outI = out + (size_t)BB * HIDD * TT * NN;

    float* ws     = (float*)d_ws;
    float* XA     = ws;                                   // 8,388,608 f
    float* hstage = XA + (size_t)TT * BB * NN * G4;       // 2,097,152 f
    float* Wpos   = hstage + (size_t)TT * BB * NN * HIDD; //     4,096 f
    float* biasP  = Wpos + 4 * G4;                        //     1,024 f
    float* c0     = biasP + G4;                           //    65,536 f
    float* c1     = c0 + (size_t)BB * NN * HIDD;          //    65,536 f
    unsigned short* HP16 = (unsigned short*)(c1 + (size_t)BB * NN * HIDD); // 262,144 us
    unsigned short* WXf  = HP16 + (size_t)BB * NN * G4;   // 163,840 us
    unsigned short* WHf  = WXf + (size_t)64 * 5 * 512;    // 262,144 us
    unsigned short* xf   = WHf + (size_t)64 * 8 * 512;    // 1,310,720 us
    unsigned short* hb   = xf + (size_t)128 * 4 * 5 * 512;//    65,536 us
    int* idxw = (int*)(hb + (size_t)BB * NN * HIDD);      //   131,072 i

    ktrans2<<<64, 256, 0, stream>>>(W, bias, WXf, WHf, Wpos, biasP);
    ktopk<<<128, 256, 0, stream>>>(in, idxw, outI);
    kconvA<<<128, 256, 0, stream>>>(in, xf);
    kxa3<<<512, 256, 0, stream>>>(xf, WXf, biasP, XA);

    for (int t = 0; t < TT; ++t) {
        float* cp = (t & 1) ? c0 : c1;
        float* cn = (t & 1) ? c1 : c0;
        kh3<<<256, 256, 0, stream>>>(in, WHf, hb, Wpos, HP16, t);
        kup3<<<256, 1024, 0, stream>>>(XA, HP16, idxw, cp, cn, hb, hstage, t);
    }
    kout<<<128, 256, 0, stream>>>(hstage, out);
}

// Round 6
// 350.891 us; speedup vs baseline: 7.8129x; 1.1854x over previous
//
#include <hip/hip_runtime.h>
#include <math.h>

#define BB 4
#define CC 132
#define TT 32
#define NN 64
#define HIDD 256
#define G4 1024
#define CIN 392
#define KK 16
#define HOFF 136   // CC + OFF: start of h columns in W

typedef __attribute__((ext_vector_type(8))) short bf16x8;
typedef __attribute__((ext_vector_type(4))) float f32x4;

__device__ __forceinline__ float fsigm(float x) { return 1.0f / (1.0f + __expf(-x)); }
__device__ __forceinline__ float ftanh(float x) { float e = __expf(2.0f * x); return 1.0f - 2.0f / (e + 1.0f); }
__device__ __forceinline__ unsigned short f2bf(float x) {
    union { float f; unsigned u; } v; v.f = x;
    unsigned r = v.u + 0x7fffu + ((v.u >> 16) & 1u);   // RNE
    return (unsigned short)(r >> 16);
}

// ---------------------------------------------------------------------------
// W -> MFMA fragments, gate-interleaved permutation g' = 4*j + gate
// (orig row = gate*256 + j).  WXf: K=160 x-side (A-or-B frag, sign-folded pos).
// WHf: K=256 h-side, lane&15 = g' (used as A-frag rows in kstep).
// WposA: pos k-slice A-frag (c<4 real, rest 0). biasP permuted.
// grid = 64 (g'-tiles of 16), block = 256.
// ---------------------------------------------------------------------------
__global__ __launch_bounds__(256) void ktrans2(const float* __restrict__ W,
                                               const float* __restrict__ bias,
                                               unsigned short* __restrict__ WXf,
                                               unsigned short* __restrict__ WHf,
                                               unsigned short* __restrict__ WposA,
                                               float* __restrict__ biasP) {
    int gt = blockIdx.x;
    int tid = threadIdx.x;
    __shared__ float Wl[16][CIN];
    for (int row = 0; row < 16; ++row) {
        int orig = (row & 3) * 256 + gt * 4 + (row >> 2);   // gate*256 + j
        for (int c = tid; c < CIN; c += 256)
            Wl[row][c] = W[(size_t)orig * CIN + c];
    }
    __syncthreads();
    for (int f = tid; f < 320; f += 256) {           // WXf: 5 ks x 64 lanes
        int ks = f >> 6, l = f & 63;
        bf16x8 v;
        #pragma unroll
        for (int j = 0; j < 8; ++j) {
            int c = ks * 32 + (l >> 4) * 8 + j;
            float w = (c < CC) ? Wl[l & 15][c] : ((c < HOFF) ? -Wl[l & 15][c] : 0.0f);
            v[j] = (short)f2bf(w);
        }
        *(bf16x8*)&WXf[((size_t)(gt * 5 + ks)) * 512 + l * 8] = v;
    }
    for (int f = tid; f < 512; f += 256) {           // WHf: 8 ks x 64 lanes
        int ks = f >> 6, l = f & 63;
        bf16x8 v;
        #pragma unroll
        for (int j = 0; j < 8; ++j) {
            int c = HOFF + ks * 32 + (l >> 4) * 8 + j;
            v[j] = (short)f2bf(Wl[l & 15][c]);
        }
        *(bf16x8*)&WHf[((size_t)(gt * 8 + ks)) * 512 + l * 8] = v;
    }
    if (tid < 64) {                                  // WposA: 1 ks
        bf16x8 v;
        #pragma unroll
        for (int e = 0; e < 8; ++e) {
            int c = (tid >> 4) * 8 + e;
            v[e] = (c < 4) ? (short)f2bf(Wl[tid & 15][CC + c]) : (short)0;
        }
        *(bf16x8*)&WposA[(size_t)gt * 512 + tid * 8] = v;
    }
    if (tid < 16)
        biasP[gt * 16 + tid] = bias[(tid & 3) * 256 + gt * 4 + (tid >> 2)];
}

// ---------------------------------------------------------------------------
// Top-k for all t — bit-exact f32, unchanged (strictly-graded output).
// ---------------------------------------------------------------------------
__global__ __launch_bounds__(256) void ktopk(const float* __restrict__ in,
                                             int* __restrict__ idxw,
                                             float* __restrict__ outI) {
    int b = blockIdx.x & 3, t = blockIdx.x >> 2, tprev = t ? t - 1 : 0;
    int lane = threadIdx.x & 63, w = threadIdx.x >> 6;
    const float* base = in + (size_t)b * CC * TT * NN;
    float p0 = base[(0 * TT + tprev) * NN + lane];
    float p1 = base[(1 * TT + tprev) * NN + lane];
    float p2 = base[(2 * TT + tprev) * NN + lane];
    float q0 = base[(0 * TT + t) * NN + lane];
    float q1 = base[(1 * TT + t) * NN + lane];
    float q2 = base[(2 * TT + t) * NN + lane];
    for (int nn = 0; nn < 16; ++nn) {
        int n = w * 16 + nn;
        float a0 = __shfl(q0, n), a1 = __shfl(q1, n), a2 = __shfl(q2, n);
        float dx = a0 - p0, dy = a1 - p1, dz = a2 - p2;
        float s01 = __fadd_rn(__fmul_rn(dx, dx), __fmul_rn(dy, dy));
        float d = __fadd_rn(s01, __fmul_rn(dz, dz));
        unsigned long long key =
            ((unsigned long long)__float_as_uint(d) << 32) | (unsigned)lane;
        #pragma unroll
        for (int k = 2; k <= 64; k <<= 1) {
            #pragma unroll
            for (int j = k >> 1; j > 0; j >>= 1) {
                unsigned long long other = __shfl_xor(key, j);
                bool up = (lane & k) == 0;
                bool upper = (lane & j) != 0;
                bool keepMax = up ? upper : !upper;
                unsigned long long mn = key < other ? key : other;
                unsigned long long mx = key < other ? other : key;
                key = keepMax ? mx : mn;
            }
        }
        if (lane < KK) {
            int m = (int)(key & 0xffffffffu);
            idxw[((t * BB + b) * NN + n) * KK + lane] = m;
            outI[((b * TT + t) * NN + n) * KK + lane] = (float)m;
        }
    }
}

// ---------------------------------------------------------------------------
// x -> A-fragments (bf16, K padded to 160). grid = 128 (t,b), block = 256.
// ---------------------------------------------------------------------------
__global__ __launch_bounds__(256) void kconvA(const float* __restrict__ in,
                                              unsigned short* __restrict__ xf) {
    int t = blockIdx.x >> 2, b = blockIdx.x & 3;
    int tid = threadIdx.x;
    __shared__ unsigned short X[64][160];
    int n = tid & 63, cg = tid >> 6;
    for (int c = cg; c < 160; c += 4) {
        float v = 0.0f;
        if (c < CC)        v = in[(((size_t)b * CC + c) * TT + t) * NN + n];
        else if (c < HOFF) v = in[(((size_t)b * CC + (c - CC)) * TT + t) * NN + n];
        X[n][c] = f2bf(v);
    }
    __syncthreads();
    for (int i = 0; i < 5; ++i) {          // 4 mtn x 5 ks x 64 l = 1280 frags
        int f = i * 256 + tid;
        int mtn = f / 320, r = f % 320;
        int ks = r >> 6, l = r & 63;
        uint4 v = *(const uint4*)&X[mtn * 16 + (l & 15)][ks * 32 + (l >> 4) * 8];
        *(uint4*)&xf[(((size_t)(blockIdx.x * 4 + mtn)) * 5 + ks) * 512 + l * 8] = v;
    }
}

// ---------------------------------------------------------------------------
// pos -> A-frag k-slice per (t,b,mt): lane l elem e: c=(l>>4)*8+e,
// value = pos[c][tsrc][m=mt*16+(l&15)] for c<4 else 0. tsrc = max(t-1,0).
// grid = 128 (t,b), block = 256 (mt = tid>>6).
// ---------------------------------------------------------------------------
__global__ __launch_bounds__(256) void kposA(const float* __restrict__ in,
                                             unsigned short* __restrict__ posAf) {
    int t = blockIdx.x >> 2, b = blockIdx.x & 3;
    int tsrc = t ? t - 1 : 0;
    int mt = threadIdx.x >> 6, l = threadIdx.x & 63;
    bf16x8 v;
    #pragma unroll
    for (int e = 0; e < 8; ++e) {
        int c = (l >> 4) * 8 + e;
        float p = (c < 4) ? in[(((size_t)b * CC + c) * TT + tsrc) * NN + mt * 16 + (l & 15)] : 0.0f;
        v[e] = (short)f2bf(p);
    }
    *(bf16x8*)&posAf[(((size_t)(t * BB + b)) * 4 + mt) * 512 + l * 8] = v;
}

// ---------------------------------------------------------------------------
// XA = x*Wx + biasP (MFMA, permuted cols). grid = 512, block = 256 (4 waves).
// ---------------------------------------------------------------------------
__global__ __launch_bounds__(256) void kxa3(const unsigned short* __restrict__ xf,
                                            const unsigned short* __restrict__ WXf,
                                            const float* __restrict__ biasP,
                                            float* __restrict__ XA) {
    int gq = blockIdx.x & 3, tb = blockIdx.x >> 2;
    int w = threadIdx.x >> 6, l = threadIdx.x & 63;
    int gbase = gq * 16 + w * 4;
    f32x4 acc[4][4];
    #pragma unroll
    for (int a = 0; a < 4; ++a)
        #pragma unroll
        for (int g = 0; g < 4; ++g) acc[a][g] = (f32x4){0.f, 0.f, 0.f, 0.f};
    #pragma unroll
    for (int ks = 0; ks < 5; ++ks) {
        bf16x8 af[4], bfr[4];
        #pragma unroll
        for (int m = 0; m < 4; ++m)
            af[m] = *(const bf16x8*)&xf[(((size_t)(tb * 4 + m)) * 5 + ks) * 512 + l * 8];
        #pragma unroll
        for (int g = 0; g < 4; ++g)
            bfr[g] = *(const bf16x8*)&WXf[((size_t)((gbase + g) * 5 + ks)) * 512 + l * 8];
        #pragma unroll
        for (int m = 0; m < 4; ++m)
            #pragma unroll
            for (int g = 0; g < 4; ++g)
                acc[m][g] = __builtin_amdgcn_mfma_f32_16x16x32_bf16(af[m], bfr[g], acc[m][g], 0, 0, 0);
    }
    int rb = tb * 64;
    #pragma unroll
    for (int g = 0; g < 4; ++g) {
        int gcol = (gbase + g) * 16 + (l & 15);
        float bv = biasP[gcol];
        #pragma unroll
        for (int m = 0; m < 4; ++m)
            #pragma unroll
            for (int r = 0; r < 4; ++r) {
                int row = rb + m * 16 + (l >> 4) * 4 + r;
                XA[(size_t)row * G4 + gcol] = acc[m][g][r] + bv;
            }
    }
}

// ---------------------------------------------------------------------------
// Fused per-step kernel: HP-slice GEMM into LDS + LSTM cell + max over K.
// grid = 256: b = bid&3, q = (bid>>2)&15 (j-slice of 16), nh = bid>>6 (n/4).
// block = 512 (8 waves).
// Phase 1: gatesT[g'local 64][m 64] via MFMA (D row=g', col=m) -> LDS
//          [m][68 pad] as f32x4 per (m, j_local). 9th k-slice = pos term.
// Phase 2: thread (kh, n_local, j_local): 8 k's serial, LDS gather of gates,
//          cell, max; pair-combine via LDS; write c, hstage, h-fragment.
// ---------------------------------------------------------------------------
__global__ __launch_bounds__(512) void kstep(const float* __restrict__ XA,
                                             const unsigned short* __restrict__ WHf,
                                             const unsigned short* __restrict__ WposA,
                                             const unsigned short* __restrict__ posAf,
                                             const unsigned short* __restrict__ hr,
                                             unsigned short* __restrict__ hw,
                                             const int* __restrict__ idxw,
                                             const float* __restrict__ cp,
                                             float* __restrict__ cn,
                                             float* __restrict__ hstage, int t) {
    int bid = blockIdx.x;
    int b = bid & 3, q = (bid >> 2) & 15, nh = bid >> 6;
    int tid = threadIdx.x;
    __shared__ float LDSG[64][68];          // [m][g'local(64)+pad]
    __shared__ int sidx[256];               // [n_local(16)][k(16)]
    __shared__ float cmbH[256], cmbC[256];

    if (tid < 256)
        sidx[tid] = idxw[((size_t)(t * BB + b) * NN + nh * 16 + (tid >> 4)) * KK + (tid & 15)];

    // ---------------- phase 1 ----------------
    {
        int wv = tid >> 6, l = tid & 63;
        int mt = wv & 3, gh = wv >> 2;
        bf16x8 bf[8];
        if (t > 0) {
            #pragma unroll
            for (int ks = 0; ks < 8; ++ks)
                bf[ks] = *(const bf16x8*)&hr[(((size_t)(b * 4 + mt)) * 8 + ks) * 512 + l * 8];
        }
        bf16x8 bp = *(const bf16x8*)&posAf[(((size_t)(t * BB + b)) * 4 + mt) * 512 + l * 8];
        #pragma unroll
        for (int gg = 0; gg < 2; ++gg) {
            int gtl = gh * 2 + gg;
            int gt = q * 4 + gtl;
            f32x4 a = {0.f, 0.f, 0.f, 0.f};
            if (t > 0) {
                #pragma unroll
                for (int ks = 0; ks < 8; ++ks) {
                    bf16x8 af = *(const bf16x8*)&WHf[(((size_t)gt) * 8 + ks) * 512 + l * 8];
                    a = __builtin_amdgcn_mfma_f32_16x16x32_bf16(af, bf[ks], a, 0, 0, 0);
                }
            }
            bf16x8 ap = *(const bf16x8*)&WposA[(size_t)gt * 512 + l * 8];
            a = __builtin_amdgcn_mfma_f32_16x16x32_bf16(ap, bp, a, 0, 0, 0);
            // D: row = g'local = gtl*16 + (l>>4)*4 + reg, col = m = mt*16 + (l&15)
            *(f32x4*)&LDSG[mt * 16 + (l & 15)][gtl * 16 + (l >> 4) * 4] = a;
        }
    }
    __syncthreads();
    // ---------------- phase 2 ----------------
    {
        int kh = tid >> 8, p = tid & 255;
        int nl = p >> 4, jl = p & 15;
        int n = nh * 16 + nl;
        int jg = q * 16 + jl;
        const float4 xav = *(const float4*)&XA[((size_t)(t * BB + b) * NN + n) * G4 + jg * 4];
        float hmax = -INFINITY, cmax = -INFINITY;
        #pragma unroll
        for (int kk = 0; kk < 8; ++kk) {
            int m = sidx[nl * 16 + kh * 8 + kk];
            f32x4 g = *(const f32x4*)&LDSG[m][jl * 4];
            float gi = xav.x + g[0];
            float gf = xav.y + g[1];
            float go = xav.z + g[2];
            float gg = xav.w + g[3];
            float cg = (t > 0) ? cp[((size_t)b * NN + m) * HIDD + jg] : 0.0f;
            float ck = fsigm(gf) * cg + fsigm(gi) * ftanh(gg);
            float hk = fsigm(go) * ftanh(ck);
            hmax = fmaxf(hmax, hk);
            cmax = fmaxf(cmax, ck);
        }
        if (kh == 1) { cmbH[p] = hmax; cmbC[p] = cmax; }
        __syncthreads();
        if (kh == 0) {
            hmax = fmaxf(hmax, cmbH[p]);
            cmax = fmaxf(cmax, cmbC[p]);
            cn[((size_t)b * NN + n) * HIDD + jg] = cmax;
            hstage[((size_t)(t * BB + b) * NN + n) * HIDD + jg] = hmax;
            hw[(((size_t)(b * 4 + (n >> 4))) * 8 + (jg >> 5)) * 512 +
               (((jg >> 3) & 3) * 16 + (n & 15)) * 8 + (jg & 7)] = f2bf(hmax);
        }
    }
}

// ---------------------------------------------------------------------------
// hstage [t][b][n][j] -> out [b][j][t][n] via LDS transpose. grid = 128 (t,b).
// ---------------------------------------------------------------------------
__global__ __launch_bounds__(256) void kout(const float* __restrict__ hs,
                                            float* __restrict__ out) {
    int t = blockIdx.x >> 2, b = blockIdx.x & 3;
    __shared__ float T[64][65];
    int tl = threadIdx.x & 63, th = threadIdx.x >> 6;
    for (int jc = 0; jc < 4; ++jc) {
        __syncthreads();
        for (int i = 0; i < 16; ++i) {
            int n = i * 4 + th;
            T[n][tl] = hs[((size_t)(t * BB + b) * NN + n) * HIDD + jc * 64 + tl];
        }
        __syncthreads();
        for (int i = 0; i < 16; ++i) {
            int j = jc * 64 + i * 4 + th;
            out[((size_t)(b * HIDD + j) * TT + t) * NN + tl] = T[tl][i * 4 + th];
        }
    }
}

// ---------------------------------------------------------------------------
extern "C" void kernel_launch(void* const* d_in, const int* in_sizes, int n_in,
                              void* d_out, int out_size, void* d_ws, size_t ws_size,
                              hipStream_t stream) {
    const float* in   = (const float*)d_in[0];
    const float* W    = (const float*)d_in[2];
    const float* bias = (const float*)d_in[3];
    float* out  = (float*)d_out;
    float* outI = out + (size_t)BB * HIDD * TT * NN;

    float* ws     = (float*)d_ws;
    float* XA     = ws;                                   // 8,388,608 f
    float* hstage = XA + (size_t)TT * BB * NN * G4;       // 2,097,152 f
    float* biasP  = hstage + (size_t)TT * BB * NN * HIDD; //     1,024 f
    float* c0     = biasP + G4;                           //    65,536 f
    float* c1     = c0 + (size_t)BB * NN * HIDD;          //    65,536 f
    unsigned short* WXf   = (unsigned short*)(c1 + (size_t)BB * NN * HIDD); // 163,840
    unsigned short* WHf   = WXf + (size_t)64 * 5 * 512;   // 262,144 us
    unsigned short* WposA = WHf + (size_t)64 * 8 * 512;   //  32,768 us
    unsigned short* xf    = WposA + (size_t)64 * 512;     // 1,310,720 us
    unsigned short* hb0   = xf + (size_t)128 * 4 * 5 * 512; // 65,536 us
    unsigned short* hb1   = hb0 + (size_t)BB * NN * HIDD;   // 65,536 us
    unsigned short* posAf = hb1 + (size_t)BB * NN * HIDD;   // 262,144 us
    int* idxw = (int*)(posAf + (size_t)TT * BB * 4 * 512);  // 131,072 i

    ktrans2<<<64, 256, 0, stream>>>(W, bias, WXf, WHf, WposA, biasP);
    ktopk<<<128, 256, 0, stream>>>(in, idxw, outI);
    kconvA<<<128, 256, 0, stream>>>(in, xf);
    kposA<<<128, 256, 0, stream>>>(in, posAf);
    kxa3<<<512, 256, 0, stream>>>(xf, WXf, biasP, XA);

    for (int t = 0; t < TT; ++t) {
        float* cp = (t & 1) ? c0 : c1;
        float* cn = (t & 1) ? c1 : c0;
        unsigned short* hrd = (t & 1) ? hb0 : hb1;
        unsigned short* hwr = (t & 1) ? hb1 : hb0;
        kstep<<<256, 512, 0, stream>>>(XA, WHf, WposA, posAf, hrd, hwr,
                                       idxw, cp, cn, hstage, t);
    }
    kout<<<128, 256, 0, stream>>>(hstage, out);
}

// Round 7
// 350.130 us; speedup vs baseline: 7.8299x; 1.0022x over previous
//
#include <hip/hip_runtime.h>
#include <math.h>

#define BB 4
#define CC 132
#define TT 32
#define NN 64
#define HIDD 256
#define G4 1024
#define CIN 392
#define KK 16
#define HOFF 136   // CC + OFF: start of h columns in W

typedef __attribute__((ext_vector_type(8))) short bf16x8;
typedef __attribute__((ext_vector_type(4))) float f32x4;

__device__ __forceinline__ float fsigm(float x) { return 1.0f / (1.0f + __expf(-x)); }
__device__ __forceinline__ float ftanh(float x) { float e = __expf(2.0f * x); return 1.0f - 2.0f / (e + 1.0f); }
__device__ __forceinline__ unsigned short f2bf(float x) {
    union { float f; unsigned u; } v; v.f = x;
    unsigned r = v.u + 0x7fffu + ((v.u >> 16) & 1u);   // RNE
    return (unsigned short)(r >> 16);
}

// ---------------------------------------------------------------------------
// W -> MFMA fragments, gate-interleaved permutation g' = 4*j + gate
// (orig row = gate*256 + j).  WXf: K=160 x-side (sign-folded pos).
// WHf: K=256 h-side. WposA: pos k-slice A-frag. biasP permuted.
// grid = 64 (g'-tiles of 16), block = 256.
// ---------------------------------------------------------------------------
__global__ __launch_bounds__(256) void ktrans2(const float* __restrict__ W,
                                               const float* __restrict__ bias,
                                               unsigned short* __restrict__ WXf,
                                               unsigned short* __restrict__ WHf,
                                               unsigned short* __restrict__ WposA,
                                               float* __restrict__ biasP) {
    int gt = blockIdx.x;
    int tid = threadIdx.x;
    __shared__ float Wl[16][CIN];
    for (int row = 0; row < 16; ++row) {
        int orig = (row & 3) * 256 + gt * 4 + (row >> 2);   // gate*256 + j
        for (int c = tid; c < CIN; c += 256)
            Wl[row][c] = W[(size_t)orig * CIN + c];
    }
    __syncthreads();
    for (int f = tid; f < 320; f += 256) {           // WXf: 5 ks x 64 lanes
        int ks = f >> 6, l = f & 63;
        bf16x8 v;
        #pragma unroll
        for (int j = 0; j < 8; ++j) {
            int c = ks * 32 + (l >> 4) * 8 + j;
            float w = (c < CC) ? Wl[l & 15][c] : ((c < HOFF) ? -Wl[l & 15][c] : 0.0f);
            v[j] = (short)f2bf(w);
        }
        *(bf16x8*)&WXf[((size_t)(gt * 5 + ks)) * 512 + l * 8] = v;
    }
    for (int f = tid; f < 512; f += 256) {           // WHf: 8 ks x 64 lanes
        int ks = f >> 6, l = f & 63;
        bf16x8 v;
        #pragma unroll
        for (int j = 0; j < 8; ++j) {
            int c = HOFF + ks * 32 + (l >> 4) * 8 + j;
            v[j] = (short)f2bf(Wl[l & 15][c]);
        }
        *(bf16x8*)&WHf[((size_t)(gt * 8 + ks)) * 512 + l * 8] = v;
    }
    if (tid < 64) {                                  // WposA: 1 ks
        bf16x8 v;
        #pragma unroll
        for (int e = 0; e < 8; ++e) {
            int c = (tid >> 4) * 8 + e;
            v[e] = (c < 4) ? (short)f2bf(Wl[tid & 15][CC + c]) : (short)0;
        }
        *(bf16x8*)&WposA[(size_t)gt * 512 + tid * 8] = v;
    }
    if (tid < 16)
        biasP[gt * 16 + tid] = bias[(tid & 3) * 256 + gt * 4 + (tid >> 2)];
}

// ---------------------------------------------------------------------------
// Fused prep: (a) x -> A-fragments (bf16, K padded 160); (b) pos -> A-frag
// k-slice; (c) bit-exact top-k (strictly graded). grid = 128 (t,b), block 256.
// ---------------------------------------------------------------------------
__global__ __launch_bounds__(256) void kprep(const float* __restrict__ in,
                                             int* __restrict__ idxw,
                                             float* __restrict__ outI,
                                             unsigned short* __restrict__ xf,
                                             unsigned short* __restrict__ posAf) {
    int t = blockIdx.x >> 2, b = blockIdx.x & 3;
    int tid = threadIdx.x;
    int tprev = t ? t - 1 : 0;

    // ---- (a) x -> A-fragments ----
    __shared__ unsigned short X[64][160];
    {
        int n = tid & 63, cg = tid >> 6;
        for (int c = cg; c < 160; c += 4) {
            float v = 0.0f;
            if (c < CC)        v = in[(((size_t)b * CC + c) * TT + t) * NN + n];
            else if (c < HOFF) v = in[(((size_t)b * CC + (c - CC)) * TT + t) * NN + n];
            X[n][c] = f2bf(v);
        }
        __syncthreads();
        for (int i = 0; i < 5; ++i) {          // 4 mtn x 5 ks x 64 l = 1280 frags
            int f = i * 256 + tid;
            int mtn = f / 320, r = f % 320;
            int ks = r >> 6, l = r & 63;
            uint4 v = *(const uint4*)&X[mtn * 16 + (l & 15)][ks * 32 + (l >> 4) * 8];
            *(uint4*)&xf[(((size_t)(blockIdx.x * 4 + mtn)) * 5 + ks) * 512 + l * 8] = v;
        }
    }

    // ---- (b) pos A-frag (tsrc = tprev) ----
    {
        int mt = tid >> 6, l = tid & 63;
        bf16x8 v;
        #pragma unroll
        for (int e = 0; e < 8; ++e) {
            int c = (l >> 4) * 8 + e;
            float p = (c < 4) ? in[(((size_t)b * CC + c) * TT + tprev) * NN + mt * 16 + (l & 15)] : 0.0f;
            v[e] = (short)f2bf(p);
        }
        *(bf16x8*)&posAf[(((size_t)(t * BB + b)) * 4 + mt) * 512 + l * 8] = v;
    }

    // ---- (c) top-k, bit-exact f32 ----
    {
        int lane = tid & 63, w = tid >> 6;
        const float* base = in + (size_t)b * CC * TT * NN;
        float p0 = base[(0 * TT + tprev) * NN + lane];
        float p1 = base[(1 * TT + tprev) * NN + lane];
        float p2 = base[(2 * TT + tprev) * NN + lane];
        float q0 = base[(0 * TT + t) * NN + lane];
        float q1 = base[(1 * TT + t) * NN + lane];
        float q2 = base[(2 * TT + t) * NN + lane];
        for (int nn = 0; nn < 16; ++nn) {
            int n = w * 16 + nn;
            float a0 = __shfl(q0, n), a1 = __shfl(q1, n), a2 = __shfl(q2, n);
            float dx = a0 - p0, dy = a1 - p1, dz = a2 - p2;
            float s01 = __fadd_rn(__fmul_rn(dx, dx), __fmul_rn(dy, dy));
            float d = __fadd_rn(s01, __fmul_rn(dz, dz));
            unsigned long long key =
                ((unsigned long long)__float_as_uint(d) << 32) | (unsigned)lane;
            #pragma unroll
            for (int k = 2; k <= 64; k <<= 1) {
                #pragma unroll
                for (int j = k >> 1; j > 0; j >>= 1) {
                    unsigned long long other = __shfl_xor(key, j);
                    bool up = (lane & k) == 0;
                    bool upper = (lane & j) != 0;
                    bool keepMax = up ? upper : !upper;
                    unsigned long long mn = key < other ? key : other;
                    unsigned long long mx = key < other ? other : key;
                    key = keepMax ? mx : mn;
                }
            }
            if (lane < KK) {
                int m = (int)(key & 0xffffffffu);
                idxw[((t * BB + b) * NN + n) * KK + lane] = m;
                outI[((b * TT + t) * NN + n) * KK + lane] = (float)m;
            }
        }
    }
}

// ---------------------------------------------------------------------------
// XA = x*Wx + biasP (MFMA, permuted cols). grid = 512, block = 256 (4 waves).
// ---------------------------------------------------------------------------
__global__ __launch_bounds__(256) void kxa3(const unsigned short* __restrict__ xf,
                                            const unsigned short* __restrict__ WXf,
                                            const float* __restrict__ biasP,
                                            float* __restrict__ XA) {
    int gq = blockIdx.x & 3, tb = blockIdx.x >> 2;
    int w = threadIdx.x >> 6, l = threadIdx.x & 63;
    int gbase = gq * 16 + w * 4;
    f32x4 acc[4][4];
    #pragma unroll
    for (int a = 0; a < 4; ++a)
        #pragma unroll
        for (int g = 0; g < 4; ++g) acc[a][g] = (f32x4){0.f, 0.f, 0.f, 0.f};
    #pragma unroll
    for (int ks = 0; ks < 5; ++ks) {
        bf16x8 af[4], bfr[4];
        #pragma unroll
        for (int m = 0; m < 4; ++m)
            af[m] = *(const bf16x8*)&xf[(((size_t)(tb * 4 + m)) * 5 + ks) * 512 + l * 8];
        #pragma unroll
        for (int g = 0; g < 4; ++g)
            bfr[g] = *(const bf16x8*)&WXf[((size_t)((gbase + g) * 5 + ks)) * 512 + l * 8];
        #pragma unroll
        for (int m = 0; m < 4; ++m)
            #pragma unroll
            for (int g = 0; g < 4; ++g)
                acc[m][g] = __builtin_amdgcn_mfma_f32_16x16x32_bf16(af[m], bfr[g], acc[m][g], 0, 0, 0);
    }
    int rb = tb * 64;
    #pragma unroll
    for (int g = 0; g < 4; ++g) {
        int gcol = (gbase + g) * 16 + (l & 15);
        float bv = biasP[gcol];
        #pragma unroll
        for (int m = 0; m < 4; ++m)
            #pragma unroll
            for (int r = 0; r < 4; ++r) {
                int row = rb + m * 16 + (l >> 4) * 4 + r;
                XA[(size_t)row * G4 + gcol] = acc[m][g][r] + bv;
            }
    }
}

// ---------------------------------------------------------------------------
// Fused per-step kernel (latency-hidden): idx/XA loads first, cp gathers
// issued under phase-1 MFMA latency, out written directly (L2-merged).
// grid = 256: b = bid&3, q = (bid>>2)&15, nh = bid>>6. block = 512.
// ---------------------------------------------------------------------------
__global__ __launch_bounds__(512) void kstep(const float* __restrict__ XA,
                                             const unsigned short* __restrict__ WHf,
                                             const unsigned short* __restrict__ WposA,
                                             const unsigned short* __restrict__ posAf,
                                             const unsigned short* __restrict__ hr,
                                             unsigned short* __restrict__ hw,
                                             const int* __restrict__ idxw,
                                             const float* __restrict__ cp,
                                             float* __restrict__ cn,
                                             float* __restrict__ out, int t) {
    int bid = blockIdx.x;
    int b = bid & 3, q = (bid >> 2) & 15, nh = bid >> 6;
    int tid = threadIdx.x;
    __shared__ float LDSG[64][68];          // [m][g'local(64)+pad]
    __shared__ float cmbH[256], cmbC[256];

    // phase-2 identities
    int kh = tid >> 8, p = tid & 255;
    int nl = p >> 4, jl = p & 15;
    int n = nh * 16 + nl;
    int jg = q * 16 + jl;

    // earliest loads: this thread's 8 knn indices + its XA quad
    const int* irow = &idxw[((size_t)(t * BB + b) * NN + n) * KK + kh * 8];
    int4 mi0 = *(const int4*)irow;
    int4 mi1 = *(const int4*)(irow + 4);
    const float4 xav = *(const float4*)&XA[((size_t)(t * BB + b) * NN + n) * G4 + jg * 4];

    // ---------------- phase 1: HP-slice GEMM into LDS ----------------
    {
        int wv = tid >> 6, l = tid & 63;
        int mt = wv & 3, gh = wv >> 2;
        bf16x8 bf[8];
        if (t > 0) {
            #pragma unroll
            for (int ks = 0; ks < 8; ++ks)
                bf[ks] = *(const bf16x8*)&hr[(((size_t)(b * 4 + mt)) * 8 + ks) * 512 + l * 8];
        }
        bf16x8 bp = *(const bf16x8*)&posAf[(((size_t)(t * BB + b)) * 4 + mt) * 512 + l * 8];
        #pragma unroll
        for (int gg = 0; gg < 2; ++gg) {
            int gtl = gh * 2 + gg;
            int gt = q * 4 + gtl;
            f32x4 a = {0.f, 0.f, 0.f, 0.f};
            if (t > 0) {
                #pragma unroll
                for (int ks = 0; ks < 8; ++ks) {
                    bf16x8 af = *(const bf16x8*)&WHf[(((size_t)gt) * 8 + ks) * 512 + l * 8];
                    a = __builtin_amdgcn_mfma_f32_16x16x32_bf16(af, bf[ks], a, 0, 0, 0);
                }
            }
            bf16x8 ap = *(const bf16x8*)&WposA[(size_t)gt * 512 + l * 8];
            a = __builtin_amdgcn_mfma_f32_16x16x32_bf16(ap, bp, a, 0, 0, 0);
            // D: row = g'local = gtl*16 + (l>>4)*4 + reg, col = m = mt*16 + (l&15)
            *(f32x4*)&LDSG[mt * 16 + (l & 15)][gtl * 16 + (l >> 4) * 4] = a;
        }
    }

    // prefetch c gather under MFMA/LDS latency (depends only on idxw)
    float cgv[8] = {0.f, 0.f, 0.f, 0.f, 0.f, 0.f, 0.f, 0.f};
    if (t > 0) {
        const float* cb = cp + (size_t)b * NN * HIDD + jg;
        cgv[0] = cb[(size_t)mi0.x * HIDD];
        cgv[1] = cb[(size_t)mi0.y * HIDD];
        cgv[2] = cb[(size_t)mi0.z * HIDD];
        cgv[3] = cb[(size_t)mi0.w * HIDD];
        cgv[4] = cb[(size_t)mi1.x * HIDD];
        cgv[5] = cb[(size_t)mi1.y * HIDD];
        cgv[6] = cb[(size_t)mi1.z * HIDD];
        cgv[7] = cb[(size_t)mi1.w * HIDD];
    }
    __syncthreads();

    // ---------------- phase 2: cell + max over 8 k's ----------------
    {
        int ms[8] = {mi0.x, mi0.y, mi0.z, mi0.w, mi1.x, mi1.y, mi1.z, mi1.w};
        float hmax = -INFINITY, cmax = -INFINITY;
        #pragma unroll
        for (int kk = 0; kk < 8; ++kk) {
            int m = ms[kk];
            f32x4 g = *(const f32x4*)&LDSG[m][jl * 4];
            float gi = xav.x + g[0];
            float gf = xav.y + g[1];
            float go = xav.z + g[2];
            float gg = xav.w + g[3];
            float ck = fsigm(gf) * cgv[kk] + fsigm(gi) * ftanh(gg);
            float hk = fsigm(go) * ftanh(ck);
            hmax = fmaxf(hmax, hk);
            cmax = fmaxf(cmax, ck);
        }
        if (kh == 1) { cmbH[p] = hmax; cmbC[p] = cmax; }
        __syncthreads();
        if (kh == 0) {
            hmax = fmaxf(hmax, cmbH[p]);
            cmax = fmaxf(cmax, cmbC[p]);
            cn[((size_t)b * NN + n) * HIDD + jg] = cmax;
            out[((size_t)(b * HIDD + jg) * TT + t) * NN + n] = hmax;   // L2-merged
            hw[(((size_t)(b * 4 + (n >> 4))) * 8 + (jg >> 5)) * 512 +
               (((jg >> 3) & 3) * 16 + (n & 15)) * 8 + (jg & 7)] = f2bf(hmax);
        }
    }
}

// ---------------------------------------------------------------------------
extern "C" void kernel_launch(void* const* d_in, const int* in_sizes, int n_in,
                              void* d_out, int out_size, void* d_ws, size_t ws_size,
                              hipStream_t stream) {
    const float* in   = (const float*)d_in[0];
    const float* W    = (const float*)d_in[2];
    const float* bias = (const float*)d_in[3];
    float* out  = (float*)d_out;
    float* outI = out + (size_t)BB * HIDD * TT * NN;

    float* ws     = (float*)d_ws;
    float* XA     = ws;                                   // 8,388,608 f
    float* biasP  = XA + (size_t)TT * BB * NN * G4;       //     1,024 f
    float* c0     = biasP + G4;                           //    65,536 f
    float* c1     = c0 + (size_t)BB * NN * HIDD;          //    65,536 f
    unsigned short* WXf   = (unsigned short*)(c1 + (size_t)BB * NN * HIDD); // 163,840
    unsigned short* WHf   = WXf + (size_t)64 * 5 * 512;   // 262,144 us
    unsigned short* WposA = WHf + (size_t)64 * 8 * 512;   //  32,768 us
    unsigned short* xf    = WposA + (size_t)64 * 512;     // 1,310,720 us
    unsigned short* hb0   = xf + (size_t)128 * 4 * 5 * 512; // 65,536 us
    unsigned short* hb1   = hb0 + (size_t)BB * NN * HIDD;   // 65,536 us
    unsigned short* posAf = hb1 + (size_t)BB * NN * HIDD;   // 262,144 us
    int* idxw = (int*)(posAf + (size_t)TT * BB * 4 * 512);  // 131,072 i

    ktrans2<<<64, 256, 0, stream>>>(W, bias, WXf, WHf, WposA, biasP);
    kprep<<<128, 256, 0, stream>>>(in, idxw, outI, xf, posAf);
    kxa3<<<512, 256, 0, stream>>>(xf, WXf, biasP, XA);

    for (int t = 0; t < TT; ++t) {
        float* cpb = (t & 1) ? c0 : c1;
        float* cnb = (t & 1) ? c1 : c0;
        unsigned short* hrd = (t & 1) ? hb0 : hb1;
        unsigned short* hwr = (t & 1) ? hb1 : hb0;
        kstep<<<256, 512, 0, stream>>>(XA, WHf, WposA, posAf, hrd, hwr,
                                       idxw, cpb, cnb, out, t);
    }
}